// Round 11
// baseline (499.246 us; speedup 1.0000x reference)
//
#include <hip/hip_runtime.h>
#include <cmath>

#define N_NODES 50000
#define N_EDGES 800000
#define D_IN    128
#define D_HID   256
#define D_OUT   47
#define UPAD    48          // padded U row stride (floats): 192B = 3 aligned lines
#define BN_EPS  1e-5f
#define SCAN_NBLK ((N_NODES + 255) / 256)   // 196

typedef __attribute__((ext_vector_type(8))) short bf16x8;
typedef __attribute__((ext_vector_type(4))) float floatx4;
typedef unsigned short u16;
typedef unsigned int u32;

__device__ __forceinline__ short f2bf(float f) {          // legacy (short)
    unsigned u = __float_as_uint(f);
    u += 0x7fff + ((u >> 16) & 1);
    return (short)(u >> 16);
}
__device__ __forceinline__ u16 f2bf_u(float f) {
    unsigned u = __float_as_uint(f);
    u += 0x7fff + ((u >> 16) & 1);
    return (u16)(u >> 16);
}
__device__ __forceinline__ float bf2f(u16 h) {
    return __uint_as_float(((unsigned)h) << 16);
}

// async 16B global->LDS DMA (the op hipcc cannot sink; tracked by vmcnt)
__device__ __forceinline__ void load_lds16(const void* g, void* l) {
    __builtin_amdgcn_global_load_lds(
        (const __attribute__((address_space(1))) u32*)g,
        (__attribute__((address_space(3))) u32*)l,
        16, 0, 0);
}

// ---------------------------------------------------------------------------
// edge_index layout detection (int64 vs int32)
// ---------------------------------------------------------------------------
__global__ void detect_idx_kernel(const int* __restrict__ ei, int* __restrict__ flag) {
    __shared__ int any_nonzero;
    if (threadIdx.x == 0) any_nonzero = 0;
    __syncthreads();
    int v = ei[2 * threadIdx.x + 1];
    if (v != 0) atomicAdd(&any_nonzero, 1);
    __syncthreads();
    if (threadIdx.x == 0) *flag = (any_nonzero == 0) ? 1 : 0;
}

__device__ __forceinline__ int load_edge(const int* __restrict__ ei, int e, int which, int is64) {
    if (is64) return ei[2 * ((long long)which * N_EDGES + e)];
    return ei[(long long)which * N_EDGES + e];
}

// ---------------------------------------------------------------------------
// CSR build
// ---------------------------------------------------------------------------
__global__ void count_deg_kernel(const int* __restrict__ ei, const int* __restrict__ flag,
                                 int* __restrict__ degi) {
    int e = blockIdx.x * blockDim.x + threadIdx.x;
    if (e >= N_EDGES) return;
    int is64 = *flag;
    atomicAdd(&degi[load_edge(ei, e, 1, is64)], 1);
}

__global__ __launch_bounds__(256) void block_sum_kernel(const int* __restrict__ degi,
                                                        int* __restrict__ bsum) {
    const int i = blockIdx.x * 256 + threadIdx.x;
    int v = (i < N_NODES) ? degi[i] : 0;
#pragma unroll
    for (int off = 32; off > 0; off >>= 1) v += __shfl_down(v, off);
    __shared__ int sh[4];
    if ((threadIdx.x & 63) == 0) sh[threadIdx.x >> 6] = v;
    __syncthreads();
    if (threadIdx.x == 0) bsum[blockIdx.x] = sh[0] + sh[1] + sh[2] + sh[3];
}

__global__ __launch_bounds__(256) void scan_bsums_kernel(int* __restrict__ bsum,
                                                         int* __restrict__ row_ptr) {
    const int t = threadIdx.x;
    __shared__ int sh[256];
    int v = (t < SCAN_NBLK) ? bsum[t] : 0;
    sh[t] = v;
    __syncthreads();
#pragma unroll
    for (int off = 1; off < 256; off <<= 1) {
        int u = (t >= off) ? sh[t - off] : 0;
        __syncthreads();
        sh[t] += u;
        __syncthreads();
    }
    if (t < SCAN_NBLK) bsum[t] = sh[t] - v;
    if (t == 255) row_ptr[N_NODES] = sh[255];
}

__global__ __launch_bounds__(256) void fill_rowptr_kernel(const int* __restrict__ degi,
                                                          const int* __restrict__ bsum,
                                                          int* __restrict__ row_ptr,
                                                          int* __restrict__ cursor,
                                                          float* __restrict__ invd) {
    const int t = threadIdx.x;
    const int i = blockIdx.x * 256 + t;
    __shared__ int sh[256];
    int d = (i < N_NODES) ? degi[i] : 0;
    sh[t] = d;
    __syncthreads();
#pragma unroll
    for (int off = 1; off < 256; off <<= 1) {
        int u = (t >= off) ? sh[t - off] : 0;
        __syncthreads();
        sh[t] += u;
        __syncthreads();
    }
    if (i < N_NODES) {
        const int pos = bsum[blockIdx.x] + sh[t] - d;
        row_ptr[i] = pos;
        cursor[i]  = pos;
        invd[i]    = 1.0f / fmaxf((float)d, 1.0f);
    }
}

__global__ void fill_csr_kernel(const int* __restrict__ ei, const int* __restrict__ flag,
                                int* __restrict__ cursor, int* __restrict__ ssrc) {
    int e = blockIdx.x * blockDim.x + threadIdx.x;
    if (e >= N_EDGES) return;
    int is64 = *flag;
    int s = load_edge(ei, e, 0, is64);
    int d = load_edge(ei, e, 1, is64);
    int pos = atomicAdd(&cursor[d], 1);
    ssrc[pos] = s;
}

// ===========================================================================
// FULL (bf16-direct) path kernels
// ===========================================================================

// x (fp32) -> xb (bf16), N*128 elems
__global__ void convert_xb_kernel(const float* __restrict__ x, u16* __restrict__ xb) {
    const int n4 = N_NODES * D_IN / 4;
    int i = blockIdx.x * 256 + threadIdx.x;
    if (i >= n4) return;
    float4 v = ((const float4*)x)[i];
    ushort4 o;
    o.x = f2bf_u(v.x); o.y = f2bf_u(v.y); o.z = f2bf_u(v.z); o.w = f2bf_u(v.w);
    ((ushort4*)xb)[i] = o;
}

// all weights -> bf16, k-blocked layout: WT[kb][col][32] (kb = k/32).
// WT3 = [W3_l | W3_r | 0pad] (128 cols x 256 k)
__global__ void build_wt_kernel(const float* __restrict__ W1l, const float* __restrict__ W1r,
                                const float* __restrict__ W2l, const float* __restrict__ W2r,
                                const float* __restrict__ W3l, const float* __restrict__ W3r,
                                u16* __restrict__ wt1l, u16* __restrict__ wt1r,
                                u16* __restrict__ wt2l, u16* __restrict__ wt2r,
                                u16* __restrict__ wt3) {
    int idx = blockIdx.x * 256 + threadIdx.x;
    if (idx < 65536) {                       // WT1l / WT1r : NC=256, K=128
        int seg = idx >> 15, d = idx & 32767;
        int kb = d >> 13, col = (d >> 5) & 255, kq = d & 31;
        int k = kb * 32 + kq;
        const float* W = seg ? W1r : W1l;
        u16* WT = seg ? wt1r : wt1l;
        WT[d] = f2bf_u(W[k * 256 + col]);
    } else if (idx < 196608) {               // WT2l / WT2r : NC=256, K=256
        int d = idx - 65536;
        int seg = d >> 16; d &= 65535;
        int kb = d >> 13, col = (d >> 5) & 255, kq = d & 31;
        int k = kb * 32 + kq;
        const float* W = seg ? W2r : W2l;
        u16* WT = seg ? wt2r : wt2l;
        WT[d] = f2bf_u(W[k * 256 + col]);
    } else if (idx < 229376) {               // WT3 : NC=128, K=256, zero-padded
        int d = idx - 196608;
        int kb = d >> 12, col = (d >> 5) & 127, kq = d & 31;
        int k = kb * 32 + kq;
        float v = 0.f;
        if (col < 47)      v = W3l[k * 47 + col];
        else if (col < 94) v = W3r[k * 47 + (col - 47)];
        wt3[d] = f2bf_u(v);
    }
}

// CSR gather-mean over bf16 rows: one wave per node, HALF-WAVE EDGE PAIRING.
// R10 showed 8-way unroll over 64-lane rows gained ~0 -> not MLP-bound.
// New mechanism: 32 lanes x 16B (CC=256) / 8B (CC=128) cover one row, and the
// two half-waves process edges e (half 0) and e+1 (half 1) simultaneously ->
// HALF the VMEM instructions for the same bytes; final __shfl_xor(.,32) + add
// merges halves; lanes 0-31 store the row (32x16B = full 512B row).
// 4-pair inner unroll keeps 4 loads in flight per lane (8 edges/wave/iter).
template <int CC>
__global__ __launch_bounds__(256) void gather_mean_bf(
    const u16* __restrict__ Xb, const int* __restrict__ rp,
    const int* __restrict__ ssrc, const float* __restrict__ invd,
    u16* __restrict__ agg)
{
    const int w = (blockIdx.x * 256 + threadIdx.x) >> 6;
    const int lane = threadIdx.x & 63;
    if (w >= N_NODES) return;
    const int start = rp[w], end = rp[w + 1];
    const float sc = invd[w];
    const int l5 = lane & 31, half = lane >> 5;

    if constexpr (CC == 256) {
        const u16* base = Xb + l5 * 8;          // 32 lanes x 8 u16 = 512B row
        float a[8];
#pragma unroll
        for (int i = 0; i < 8; ++i) a[i] = 0.f;

        int e = start;
        for (; e + 7 < end; e += 8) {           // 4 pairs: 4 loads in flight/lane
            bf16x8 v0 = *(const bf16x8*)(base + (size_t)ssrc[e     + half] * 256);
            bf16x8 v1 = *(const bf16x8*)(base + (size_t)ssrc[e + 2 + half] * 256);
            bf16x8 v2 = *(const bf16x8*)(base + (size_t)ssrc[e + 4 + half] * 256);
            bf16x8 v3 = *(const bf16x8*)(base + (size_t)ssrc[e + 6 + half] * 256);
#pragma unroll
            for (int i = 0; i < 8; ++i)
                a[i] += (bf2f((u16)v0[i]) + bf2f((u16)v1[i]))
                      + (bf2f((u16)v2[i]) + bf2f((u16)v3[i]));
        }
        for (; e < end; e += 2) {               // pair tail (half 1 may idle)
            if (e + half < end) {
                bf16x8 v = *(const bf16x8*)(base + (size_t)ssrc[e + half] * 256);
#pragma unroll
                for (int i = 0; i < 8; ++i) a[i] += bf2f((u16)v[i]);
            }
        }
#pragma unroll
        for (int i = 0; i < 8; ++i) a[i] += __shfl_xor(a[i], 32);
        if (half == 0) {
            bf16x8 o;
#pragma unroll
            for (int i = 0; i < 8; ++i) o[i] = (short)f2bf_u(a[i] * sc);
            *(bf16x8*)(agg + (size_t)w * 256 + l5 * 8) = o;
        }
    } else {  // CC == 128: 32 lanes x 4 u16 = 256B row
        const u16* base = Xb + l5 * 4;
        float a[4];
#pragma unroll
        for (int i = 0; i < 4; ++i) a[i] = 0.f;

        int e = start;
        for (; e + 7 < end; e += 8) {
            ushort4 v0 = *(const ushort4*)(base + (size_t)ssrc[e     + half] * 128);
            ushort4 v1 = *(const ushort4*)(base + (size_t)ssrc[e + 2 + half] * 128);
            ushort4 v2 = *(const ushort4*)(base + (size_t)ssrc[e + 4 + half] * 128);
            ushort4 v3 = *(const ushort4*)(base + (size_t)ssrc[e + 6 + half] * 128);
            a[0] += (bf2f(v0.x) + bf2f(v1.x)) + (bf2f(v2.x) + bf2f(v3.x));
            a[1] += (bf2f(v0.y) + bf2f(v1.y)) + (bf2f(v2.y) + bf2f(v3.y));
            a[2] += (bf2f(v0.z) + bf2f(v1.z)) + (bf2f(v2.z) + bf2f(v3.z));
            a[3] += (bf2f(v0.w) + bf2f(v1.w)) + (bf2f(v2.w) + bf2f(v3.w));
        }
        for (; e < end; e += 2) {
            if (e + half < end) {
                ushort4 v = *(const ushort4*)(base + (size_t)ssrc[e + half] * 128);
                a[0] += bf2f(v.x); a[1] += bf2f(v.y);
                a[2] += bf2f(v.z); a[3] += bf2f(v.w);
            }
        }
#pragma unroll
        for (int i = 0; i < 4; ++i) a[i] += __shfl_xor(a[i], 32);
        if (half == 0) {
            ushort4 o;
            o.x = f2bf_u(a[0] * sc); o.y = f2bf_u(a[1] * sc);
            o.z = f2bf_u(a[2] * sc); o.w = f2bf_u(a[3] * sc);
            *(ushort4*)(agg + (size_t)w * 128 + l5 * 4) = o;
        }
    }
}

// ---------------------------------------------------------------------------
// LDS-staged bf16 MFMA GEMM, T3+T4 (proven R8): counted vmcnt + XCD swizzle.
// split>0 path writes U with PADDED row stride UPAD=48 floats (192B-aligned
// rows -> the downstream random gather touches exactly 3 cache lines/row).
// ---------------------------------------------------------------------------
template <int NK0, int NK1, int NC>
__global__ __launch_bounds__(256, 2) void mfma_lds(
    const u16* __restrict__ A0, const u16* __restrict__ WT0,
    const u16* __restrict__ A1, const u16* __restrict__ WT1,
    const float* __restrict__ bias,
    const float* __restrict__ gamma, const float* __restrict__ beta,
    const float* __restrict__ mean, const float* __restrict__ var,
    float* __restrict__ C, int M, int do_bias, int bn_relu,
    u16* __restrict__ Cb, float* __restrict__ C2, int split)
{
    __shared__ __align__(16) char lds[24576];   // A dbuf @0/8192, B dbuf @16384/20480

    constexpr int NYB = (N_NODES + 127) / 128;  // 391 row-panels
    constexpr int nxb = NC / 64;                // col-blocks per row-panel

    // ---- XCD col-sibling swizzle (1-D grid, nxb*8*ceil(NYB/8) blocks)
    const int bid  = blockIdx.x;
    const int xcd  = bid & 7;
    const int slot = bid >> 3;
    const int cb   = slot % nxb;
    const int yg   = slot / nxb;
    const int yb   = yg * 8 + xcd;
    if (yb >= NYB) return;                      // pad guard (uniform per block)

    const int t = threadIdx.x;
    const int wv = t >> 6, lane = t & 63;
    const int lr = lane & 15, quad = lane >> 4;
    const int row0 = yb * 128;
    const int col0 = cb * 64;
    constexpr int NKT = NK0 + NK1;

    // ---- per-thread stage constants
    // A: 2 slots of 16B (8KB tile); B: 1 slot of 16B (4KB tile)
    int sIdxA[2], sCsA[2];
#pragma unroll
    for (int i = 0; i < 2; ++i) {
        int slotA = i * 256 + t;           // 0..511
        sIdxA[i] = slotA >> 2;             // row 0..127
        int c = slotA & 3;
        sCsA[i] = c ^ ((sIdxA[i] >> 1) & 3);
    }
    int srowA[2];
#pragma unroll
    for (int i = 0; i < 2; ++i) {
        int r = row0 + sIdxA[i];
        srowA[i] = (r < N_NODES) ? r : (N_NODES - 1);   // clamp (garbage rows unused)
    }
    const int sIdxB = t >> 2;              // col 0..63
    const int sCsB  = (t & 3) ^ ((sIdxB >> 1) & 3);

    // ---- ds_read byte offsets within a tile (swizzled chunk)
    int offA[2], offB[4];
#pragma unroll
    for (int r = 0; r < 2; ++r) {
        int idx = wv * 32 + r * 16 + lr;
        offA[r] = idx * 64 + ((quad ^ ((idx >> 1) & 3)) * 16);
    }
#pragma unroll
    for (int c = 0; c < 4; ++c) {
        int idx = c * 16 + lr;
        offB[c] = idx * 64 + ((quad ^ ((idx >> 1) & 3)) * 16);
    }

    floatx4 acc[2][4];
#pragma unroll
    for (int r = 0; r < 2; ++r)
#pragma unroll
        for (int c = 0; c < 4; ++c) acc[r][c] = (floatx4){0.f, 0.f, 0.f, 0.f};

    // ---- stage k-step ks into buffer 'cur' (3 loads/thread, vmcnt-tracked)
    auto stage = [&](int ks, int cur) {
        const char* Ab; const char* Wb; int kb; size_t Kb;  // Kb = row stride bytes
        if (ks < NK0) { Ab = (const char*)A0; Wb = (const char*)WT0; kb = ks;       Kb = (size_t)NK0 * 64; }
        else          { Ab = (const char*)A1; Wb = (const char*)WT1; kb = ks - NK0; Kb = (size_t)NK1 * 64; }
#pragma unroll
        for (int i = 0; i < 2; ++i) {
            const char* srcA = Ab + (size_t)srowA[i] * Kb + (size_t)kb * 64 + sCsA[i] * 16;
            load_lds16(srcA, lds + cur * 8192 + (i * 256 + t) * 16);
        }
        const char* srcB = Wb + ((size_t)kb * NC + col0 + sIdxB) * 64 + sCsB * 16;
        load_lds16(srcB, lds + 16384 + cur * 4096 + t * 16);
    };

    // ---- compute current buffer: 2 A-frags + 4 B-frags + 8 MFMA
    auto compute = [&](int cur) {
        const char* la = lds + cur * 8192;
        const char* lb = lds + 16384 + cur * 4096;
        bf16x8 a[2], b[4];
#pragma unroll
        for (int r = 0; r < 2; ++r) a[r] = *(const bf16x8*)(la + offA[r]);
#pragma unroll
        for (int c = 0; c < 4; ++c) b[c] = *(const bf16x8*)(lb + offB[c]);
#pragma unroll
        for (int c = 0; c < 4; ++c) {
            acc[0][c] = __builtin_amdgcn_mfma_f32_16x16x32_bf16(a[0], b[c], acc[0][c], 0, 0, 0);
            acc[1][c] = __builtin_amdgcn_mfma_f32_16x16x32_bf16(a[1], b[c], acc[1][c], 0, 0, 0);
        }
    };

    // ---- T4 counted-vmcnt main loop: stages ks and ks+1 in flight; never
    //      drain to 0 until the final stage.
    stage(0, 0);
    if constexpr (NKT > 1) stage(1, 1);
#pragma unroll
    for (int ks = 0; ks < NKT; ++ks) {
        if (ks < NKT - 1) {
            asm volatile("s_waitcnt vmcnt(3)" ::: "memory");   // stage ks landed (3 of ks+1 in flight)
        } else {
            asm volatile("s_waitcnt vmcnt(0)" ::: "memory");   // final stage
        }
        __builtin_amdgcn_s_barrier();        // all waves' stage(ks) visible
        __builtin_amdgcn_sched_barrier(0);   // pin: no hoist of ds_read above barrier
        compute(ks & 1);
        if (ks + 2 < NKT) {
            __builtin_amdgcn_s_barrier();    // all waves done reading buf[ks&1]
            stage(ks + 2, ks & 1);           // refill freed buffer; loads fly on
        }
    }

    // ---- epilogue (C/D: col=lr, row=quad*4+g) — proven round-0 mapping
#pragma unroll
    for (int r = 0; r < 2; ++r) {
#pragma unroll
        for (int g = 0; g < 4; ++g) {
            const int row = row0 + wv * 32 + r * 16 + quad * 4 + g;
            if (row >= N_NODES) continue;
#pragma unroll
            for (int c = 0; c < 4; ++c) {
                const int col = col0 + c * 16 + lr;
                float v = acc[r][c][g];
                if (split > 0) {
                    if (col < split) {
                        C[(size_t)row * UPAD + col] = v;     // padded U rows (192B)
                    } else if (col < 2 * split) {
                        C2[(size_t)row * split + (col - split)] = v + bias[col - split];
                    }
                } else {
                    if (col >= M) continue;
                    if (do_bias) v += bias[col];
                    if (bn_relu) {
                        v = (v - mean[col]) * (gamma[col] * rsqrtf(var[col] + BN_EPS)) + beta[col];
                        v = fmaxf(v, 0.0f);
                    }
                    const size_t off = (size_t)row * M + col;
                    C[off] = v;
                    if (Cb) Cb[off] = f2bf_u(v);
                }
            }
        }
    }
}

// ===========================================================================
// SAFE path kernels (R5, proven)
// ===========================================================================
template <int CC>
__global__ __launch_bounds__(256) void gather_mean(
    const float* __restrict__ X, int ldx,
    const int* __restrict__ rp, const int* __restrict__ ssrc,
    const float* __restrict__ invd, float* __restrict__ agg)
{
    const long long gid = (long long)blockIdx.x * blockDim.x + threadIdx.x;
    const int w = (int)(gid >> 6);
    const int lane = threadIdx.x & 63;
    if (w >= N_NODES) return;
    const int start = rp[w], end = rp[w + 1];
    const float sc = invd[w];

    if constexpr (CC == 256) {
        const float* base = X + lane * 4;
        float4 a = make_float4(0.f, 0.f, 0.f, 0.f);
        int e = start;
        for (; e + 1 < end; e += 2) {
            int s0 = ssrc[e], s1 = ssrc[e + 1];
            float4 v0 = *(const float4*)(base + (long long)s0 * ldx);
            float4 v1 = *(const float4*)(base + (long long)s1 * ldx);
            a.x += v0.x + v1.x; a.y += v0.y + v1.y;
            a.z += v0.z + v1.z; a.w += v0.w + v1.w;
        }
        if (e < end) {
            float4 v = *(const float4*)(base + (long long)ssrc[e] * ldx);
            a.x += v.x; a.y += v.y; a.z += v.z; a.w += v.w;
        }
        float4 o = make_float4(a.x * sc, a.y * sc, a.z * sc, a.w * sc);
        *(float4*)(agg + (long long)w * 256 + lane * 4) = o;
    } else {
        const float* base = X + lane * 2;
        float2 a = make_float2(0.f, 0.f);
        int e = start;
        for (; e + 1 < end; e += 2) {
            int s0 = ssrc[e], s1 = ssrc[e + 1];
            float2 v0 = *(const float2*)(base + (long long)s0 * ldx);
            float2 v1 = *(const float2*)(base + (long long)s1 * ldx);
            a.x += v0.x + v1.x; a.y += v0.y + v1.y;
        }
        if (e < end) {
            float2 v = *(const float2*)(base + (long long)ssrc[e] * ldx);
            a.x += v.x; a.y += v.y;
        }
        float2 o = make_float2(a.x * sc, a.y * sc);
        *(float2*)(agg + (long long)w * 128 + lane * 2) = o;
    }
}

#define GBM 128
#define GBN 64
#define GBK 32
#define LDA 40
#define LDB 40

__global__ __launch_bounds__(256) void mfma_gemm(
    const float* __restrict__ A0, const float* __restrict__ B0, int K0,
    const float* __restrict__ A1, const float* __restrict__ B1, int K1,
    const float* __restrict__ bias,
    const float* __restrict__ gamma, const float* __restrict__ beta,
    const float* __restrict__ mean, const float* __restrict__ var,
    float* __restrict__ C, int M, int do_bias, int bn_relu)
{
    __shared__ short As[GBM * LDA];
    __shared__ short Bs[GBN * LDB];

    const int t = threadIdx.x;
    const int wv = t >> 6;
    const int lane = t & 63;
    const int row0 = blockIdx.y * GBM;
    const int col0 = blockIdx.x * GBN;

    const int lr = lane & 15;
    const int lk = (lane >> 4) * 8;

    floatx4 acc[2][4];
#pragma unroll
    for (int r = 0; r < 2; ++r)
#pragma unroll
        for (int c = 0; c < 4; ++c) acc[r][c] = (floatx4){0.f, 0.f, 0.f, 0.f};

    const int arow = t >> 3;
    const int akc  = (t & 7) * 4;
    const int bkr  = t >> 4;
    const int bcc  = (t & 15) * 4;

    for (int pass = 0; pass < 2; ++pass) {
        if (pass == 1 && A1 == nullptr) break;
        const float* __restrict__ A = pass ? A1 : A0;
        const float* __restrict__ B = pass ? B1 : B0;
        const int K = pass ? K1 : K0;

        for (int k0 = 0; k0 < K; k0 += GBK) {
            __syncthreads();
#pragma unroll
            for (int i = 0; i < 4; ++i) {
                const int lrow = arow + i * 32;
                const int grow = row0 + lrow;
                float4 v = make_float4(0.f, 0.f, 0.f, 0.f);
                if (grow < N_NODES)
                    v = *(const float4*)(A + (long long)grow * K + k0 + akc);
                short4 sv;
                sv.x = f2bf(v.x); sv.y = f2bf(v.y);
                sv.z = f2bf(v.z); sv.w = f2bf(v.w);
                *(short4*)(&As[lrow * LDA + akc]) = sv;
            }
#pragma unroll
            for (int i = 0; i < 2; ++i) {
                const int k = bkr + i * 16;
                const int gc = col0 + bcc;
                float4 v;
                if (gc + 3 < M) {
                    v = *(const float4*)(B + (long long)(k0 + k) * M + gc);
                } else {
                    v.x = (gc + 0 < M) ? B[(long long)(k0 + k) * M + gc + 0] : 0.f;
                    v.y = (gc + 1 < M) ? B[(long long)(k0 + k) * M + gc + 1] : 0.f;
                    v.z = (gc + 2 < M) ? B[(long long)(k0 + k) * M + gc + 2] : 0.f;
                    v.w = (gc + 3 < M) ? B[(long long)(k0 + k) * M + gc + 3] : 0.f;
                }
                Bs[(bcc + 0) * LDB + k] = f2bf(v.x);
                Bs[(bcc + 1) * LDB + k] = f2bf(v.y);
                Bs[(bcc + 2) * LDB + k] = f2bf(v.z);
                Bs[(bcc + 3) * LDB + k] = f2bf(v.w);
            }
            __syncthreads();

            bf16x8 af[2], bfr[4];
#pragma unroll
            for (int r = 0; r < 2; ++r)
                af[r] = *(const bf16x8*)(&As[(wv * 32 + r * 16 + lr) * LDA + lk]);
#pragma unroll
            for (int c = 0; c < 4; ++c)
                bfr[c] = *(const bf16x8*)(&Bs[(c * 16 + lr) * LDB + lk]);
#pragma unroll
            for (int r = 0; r < 2; ++r)
#pragma unroll
                for (int c = 0; c < 4; ++c)
                    acc[r][c] = __builtin_amdgcn_mfma_f32_16x16x32_bf16(
                        af[r], bfr[c], acc[r][c], 0, 0, 0);
        }
    }

#pragma unroll
    for (int r = 0; r < 2; ++r) {
#pragma unroll
        for (int g = 0; g < 4; ++g) {
            const int row = row0 + wv * 32 + r * 16 + (lane >> 4) * 4 + g;
            if (row >= N_NODES) continue;
#pragma unroll
            for (int c = 0; c < 4; ++c) {
                const int col = col0 + c * 16 + lr;
                if (col >= M) continue;
                float v = acc[r][c][g];
                if (do_bias) v += bias[col];
                if (bn_relu) {
                    v = (v - mean[col]) * (gamma[col] * rsqrtf(var[col] + BN_EPS)) + beta[col];
                    v = fmaxf(v, 0.0f);
                }
                C[(long long)row * M + col] = v;
            }
        }
    }
}

// ---------------------------------------------------------------------------
// fused epilogue: gather-add U into z, then log_softmax on the completed
// row IN-WAVE. ldu = U row stride (floats): 48 on the FULL path (padded,
// 192B-aligned rows -> 3 cache lines per random read), 47 on SAFE.
// ---------------------------------------------------------------------------
__global__ __launch_bounds__(256) void gather_add_softmax(
    const float* __restrict__ U, int ldu, const int* __restrict__ rp,
    const int* __restrict__ ssrc, const float* __restrict__ invd,
    float* __restrict__ z, float* __restrict__ y)
{
    const int w = (blockIdx.x * 256 + threadIdx.x) >> 6;
    const int lane = threadIdx.x & 63;
    if (w >= N_NODES) return;
    const bool act = lane < D_OUT;
    const int start = rp[w], end = rp[w + 1];
    const float* Ub = U + lane;

    float a0 = 0.f, a1 = 0.f, a2 = 0.f, a3 = 0.f;
    float a4 = 0.f, a5 = 0.f, a6 = 0.f, a7 = 0.f;
    if (act) {
        int e = start;
        for (; e + 7 < end; e += 8) {
            a0 += Ub[(long long)ssrc[e]     * ldu];
            a1 += Ub[(long long)ssrc[e + 1] * ldu];
            a2 += Ub[(long long)ssrc[e + 2] * ldu];
            a3 += Ub[(long long)ssrc[e + 3] * ldu];
            a4 += Ub[(long long)ssrc[e + 4] * ldu];
            a5 += Ub[(long long)ssrc[e + 5] * ldu];
            a6 += Ub[(long long)ssrc[e + 6] * ldu];
            a7 += Ub[(long long)ssrc[e + 7] * ldu];
        }
        for (; e < end; ++e) a0 += Ub[(long long)ssrc[e] * ldu];
    }
    // all 64 lanes converge here for the wave reductions
    float zv = 0.f;
    if (act) {
        zv = z[(long long)w * D_OUT + lane]
           + (((a0 + a1) + (a2 + a3)) + ((a4 + a5) + (a6 + a7))) * invd[w];
        z[(long long)w * D_OUT + lane] = zv;
    }

    float v = act ? zv : -INFINITY;
    float m = v;
#pragma unroll
    for (int off = 32; off > 0; off >>= 1) m = fmaxf(m, __shfl_down(m, off));
    m = __shfl(m, 0);

    float ev = act ? expf(v - m) : 0.0f;
    float s = ev;
#pragma unroll
    for (int off = 32; off > 0; off >>= 1) s += __shfl_down(s, off);
    s = __shfl(s, 0);

    if (act) y[(long long)w * D_OUT + lane] = v - m - logf(s);
}

// ---------------------------------------------------------------------------
// launch
// ---------------------------------------------------------------------------
extern "C" void kernel_launch(void* const* d_in, const int* in_sizes, int n_in,
                              void* d_out, int out_size, void* d_ws, size_t ws_size,
                              hipStream_t stream) {
    const float* x     = (const float*)d_in[0];
    const int*   ei    = (const int*)d_in[1];
    const float* W1_l  = (const float*)d_in[2];
    const float* b1    = (const float*)d_in[3];
    const float* W1_r  = (const float*)d_in[4];
    const float* bn1_g = (const float*)d_in[5];
    const float* bn1_b = (const float*)d_in[6];
    const float* bn1_m = (const float*)d_in[7];
    const float* bn1_v = (const float*)d_in[8];
    const float* W2_l  = (const float*)d_in[9];
    const float* b2    = (const float*)d_in[10];
    const float* W2_r  = (const float*)d_in[11];
    const float* bn2_g = (const float*)d_in[12];
    const float* bn2_b = (const float*)d_in[13];
    const float* bn2_m = (const float*)d_in[14];
    const float* bn2_v = (const float*)d_in[15];
    const float* W3_l  = (const float*)d_in[16];
    const float* b3    = (const float*)d_in[17];
    const float* W3_r  = (const float*)d_in[18];

    // --- common workspace (CSR) ---
    char* ws = (char*)d_ws;
    int*   degi    = (int*)(ws + 0);
    int*   row_ptr = (int*)(ws + 200064);
    int*   cursor  = (int*)(ws + 400128);
    float* invd    = (float*)(ws + 600192);
    int*   flag    = (int*)(ws + 800256);
    int*   bsum    = (int*)(ws + 800320);
    int*   ssrc    = (int*)(ws + 801152);          // 3.2 MB -> ends 4,001,152

    // d_out layout: z [N*47] | y_pred [N*47] | S1 [N*256] | S2 [N*256]
    float* z     = (float*)d_out;
    float* ypred = z + (long long)N_NODES * D_OUT;
    float* S1    = ypred + (long long)N_NODES * D_OUT;
    float* S2    = S1 + (long long)N_NODES * D_HID;

    // --- CSR build (shared) ---
    detect_idx_kernel<<<1, 256, 0, stream>>>(ei, flag);
    hipMemsetAsync(degi, 0, N_NODES * sizeof(int), stream);
    count_deg_kernel<<<(N_EDGES + 255) / 256, 256, 0, stream>>>(ei, flag, degi);
    block_sum_kernel<<<SCAN_NBLK, 256, 0, stream>>>(degi, bsum);
    scan_bsums_kernel<<<1, 256, 0, stream>>>(bsum, row_ptr);
    fill_rowptr_kernel<<<SCAN_NBLK, 256, 0, stream>>>(degi, bsum, row_ptr, cursor, invd);
    fill_csr_kernel<<<(N_EDGES + 255) / 256, 256, 0, stream>>>(ei, flag, cursor, ssrc);

    const int gblocks = (N_NODES * 64 + 255) / 256;

    // FULL bf16-direct plan needs 94,059,904 B of ws
    if (ws_size >= 94059904ULL) {
        u16*   wt1l = (u16*)(ws + 4001152);
        u16*   wt1r = (u16*)(ws + 4066688);
        u16*   wt2l = (u16*)(ws + 4132224);
        u16*   wt2r = (u16*)(ws + 4263296);
        u16*   wt3  = (u16*)(ws + 4394368);
        u16*   xb   = (u16*)(ws + 4459904);        // N*128 bf16
        u16*   S1b  = (u16*)(ws + 17259904);       // N*256 bf16
        u16*   S2b  = (u16*)(ws + 42859904);       // N*256 bf16
        u16*   agg  = (u16*)(ws + 68459904);       // N*256 bf16 (reused as U fp32, UPAD=48: 9.6MB < 25.6MB)
        float* U    = (float*)agg;

        convert_xb_kernel<<<(N_NODES * D_IN / 4 + 255) / 256, 256, 0, stream>>>(x, xb);
        build_wt_kernel<<<(229376 + 255) / 256, 256, 0, stream>>>(
            W1_l, W1_r, W2_l, W2_r, W3_l, W3_r, wt1l, wt1r, wt2l, wt2r, wt3);

        // 1-D swizzled grids: nxb * 8 * ceil(391/8) blocks
        const int nHid = 4 * 8 * 49;   // NC=256 -> 1568 (4 early-return)
        const int nOut = 2 * 8 * 49;   // NC=128 -> 784  (2 early-return)

        // layer 1 (K=128 x2 passes, NKT=8)
        gather_mean_bf<128><<<gblocks, 256, 0, stream>>>(xb, row_ptr, ssrc, invd, agg);
        mfma_lds<4, 4, 256><<<nHid, 256, 0, stream>>>(
            agg, wt1l, xb, wt1r,
            b1, bn1_g, bn1_b, bn1_m, bn1_v,
            S1, D_HID, 1, 1, S1b, nullptr, 0);
        // layer 2 (K=256 x2 passes, NKT=16)
        gather_mean_bf<256><<<gblocks, 256, 0, stream>>>(S1b, row_ptr, ssrc, invd, agg);
        mfma_lds<8, 8, 256><<<nHid, 256, 0, stream>>>(
            agg, wt2l, S1b, wt2r,
            b2, bn2_g, bn2_b, bn2_m, bn2_v,
            S2, D_HID, 1, 1, S2b, nullptr, 0);
        // layer 3 (fused transform-first: U = S2@W3_l [padded stride 48], z = S2@W3_r + b3)
        mfma_lds<8, 0, 128><<<nOut, 256, 0, stream>>>(
            S2b, wt3, nullptr, nullptr,
            b3, nullptr, nullptr, nullptr, nullptr,
            U, 94, 0, 0, nullptr, z, D_OUT);
        gather_add_softmax<<<gblocks, 256, 0, stream>>>(U, UPAD, row_ptr, ssrc, invd, z, ypred);
    } else {
        // SAFE: R5 fp32-LDS pipeline (proven <= 55.2 MB)
        float* aggF = (float*)(ws + 4001152);      // N*256 fp32, ends 55,201,152
        float* U    = aggF;

        const dim3 gHid(D_HID / GBN, (N_NODES + GBM - 1) / GBM);
        const dim3 gOut(1, (N_NODES + GBM - 1) / GBM);

        gather_mean<128><<<gblocks, 256, 0, stream>>>(x, D_IN, row_ptr, ssrc, invd, aggF);
        mfma_gemm<<<gHid, 256, 0, stream>>>(aggF, W1_l, D_IN, x, W1_r, D_IN,
                                            b1, bn1_g, bn1_b, bn1_m, bn1_v,
                                            S1, D_HID, 1, 1);
        gather_mean<256><<<gblocks, 256, 0, stream>>>(S1, D_HID, row_ptr, ssrc, invd, aggF);
        mfma_gemm<<<gHid, 256, 0, stream>>>(aggF, W2_l, D_HID, S1, W2_r, D_HID,
                                            b2, bn2_g, bn2_b, bn2_m, bn2_v,
                                            S2, D_HID, 1, 1);
        mfma_gemm<<<gOut, 256, 0, stream>>>(S2, W3_l, D_HID, nullptr, nullptr, 0,
                                            nullptr, nullptr, nullptr, nullptr, nullptr,
                                            U, D_OUT, 0, 0);
        mfma_gemm<<<gOut, 256, 0, stream>>>(S2, W3_r, D_HID, nullptr, nullptr, 0,
                                            b3, nullptr, nullptr, nullptr, nullptr,
                                            z, D_OUT, 1, 0);
        gather_add_softmax<<<gblocks, 256, 0, stream>>>(U, D_OUT, row_ptr, ssrc, invd, z, ypred);
    }
}

// Round 13
// 487.312 us; speedup vs baseline: 1.0245x; 1.0245x over previous
//
#include <hip/hip_runtime.h>
#include <cmath>

#define N_NODES 50000
#define N_EDGES 800000
#define D_IN    128
#define D_HID   256
#define D_OUT   47
#define UPADB   64          // padded bf16-U row stride (u16 elems): 128B = 2 aligned lines
#define BN_EPS  1e-5f
#define SCAN_NBLK ((N_NODES + 255) / 256)   // 196

typedef __attribute__((ext_vector_type(8))) short bf16x8;
typedef __attribute__((ext_vector_type(4))) float floatx4;
typedef unsigned short u16;
typedef unsigned int u32;

__device__ __forceinline__ short f2bf(float f) {          // legacy (short)
    unsigned u = __float_as_uint(f);
    u += 0x7fff + ((u >> 16) & 1);
    return (short)(u >> 16);
}
__device__ __forceinline__ u16 f2bf_u(float f) {
    unsigned u = __float_as_uint(f);
    u += 0x7fff + ((u >> 16) & 1);
    return (u16)(u >> 16);
}
__device__ __forceinline__ float bf2f(u16 h) {
    return __uint_as_float(((unsigned)h) << 16);
}

// async 16B global->LDS DMA (the op hipcc cannot sink; tracked by vmcnt)
__device__ __forceinline__ void load_lds16(const void* g, void* l) {
    __builtin_amdgcn_global_load_lds(
        (const __attribute__((address_space(1))) u32*)g,
        (__attribute__((address_space(3))) u32*)l,
        16, 0, 0);
}

// ---------------------------------------------------------------------------
// edge_index layout detection (int64 vs int32)
// ---------------------------------------------------------------------------
__global__ void detect_idx_kernel(const int* __restrict__ ei, int* __restrict__ flag) {
    __shared__ int any_nonzero;
    if (threadIdx.x == 0) any_nonzero = 0;
    __syncthreads();
    int v = ei[2 * threadIdx.x + 1];
    if (v != 0) atomicAdd(&any_nonzero, 1);
    __syncthreads();
    if (threadIdx.x == 0) *flag = (any_nonzero == 0) ? 1 : 0;
}

// ---------------------------------------------------------------------------
// CSR build — count/fill process 2 edges/thread with int2/int4 loads
// (halves VMEM ops on the two 800K-edge passes; atomics unchanged).
// ---------------------------------------------------------------------------
__global__ void count_deg_kernel(const int* __restrict__ ei, const int* __restrict__ flag,
                                 int* __restrict__ degi) {
    int e = (blockIdx.x * blockDim.x + threadIdx.x) * 2;
    if (e >= N_EDGES) return;          // N_EDGES even -> e+1 always valid
    int is64 = *flag;
    int d0, d1;
    if (is64) {
        int4 v = *(const int4*)(ei + 2 * ((size_t)N_EDGES + e));
        d0 = v.x; d1 = v.z;
    } else {
        int2 v = *(const int2*)(ei + (size_t)N_EDGES + e);
        d0 = v.x; d1 = v.y;
    }
    atomicAdd(&degi[d0], 1);
    atomicAdd(&degi[d1], 1);
}

__global__ __launch_bounds__(256) void block_sum_kernel(const int* __restrict__ degi,
                                                        int* __restrict__ bsum) {
    const int i = blockIdx.x * 256 + threadIdx.x;
    int v = (i < N_NODES) ? degi[i] : 0;
#pragma unroll
    for (int off = 32; off > 0; off >>= 1) v += __shfl_down(v, off);
    __shared__ int sh[4];
    if ((threadIdx.x & 63) == 0) sh[threadIdx.x >> 6] = v;
    __syncthreads();
    if (threadIdx.x == 0) bsum[blockIdx.x] = sh[0] + sh[1] + sh[2] + sh[3];
}

__global__ __launch_bounds__(256) void scan_bsums_kernel(int* __restrict__ bsum,
                                                         int* __restrict__ row_ptr) {
    const int t = threadIdx.x;
    __shared__ int sh[256];
    int v = (t < SCAN_NBLK) ? bsum[t] : 0;
    sh[t] = v;
    __syncthreads();
#pragma unroll
    for (int off = 1; off < 256; off <<= 1) {
        int u = (t >= off) ? sh[t - off] : 0;
        __syncthreads();
        sh[t] += u;
        __syncthreads();
    }
    if (t < SCAN_NBLK) bsum[t] = sh[t] - v;
    if (t == 255) row_ptr[N_NODES] = sh[255];
}

__global__ __launch_bounds__(256) void fill_rowptr_kernel(const int* __restrict__ degi,
                                                          const int* __restrict__ bsum,
                                                          int* __restrict__ row_ptr,
                                                          int* __restrict__ cursor,
                                                          float* __restrict__ invd) {
    const int t = threadIdx.x;
    const int i = blockIdx.x * 256 + t;
    __shared__ int sh[256];
    int d = (i < N_NODES) ? degi[i] : 0;
    sh[t] = d;
    __syncthreads();
#pragma unroll
    for (int off = 1; off < 256; off <<= 1) {
        int u = (t >= off) ? sh[t - off] : 0;
        __syncthreads();
        sh[t] += u;
        __syncthreads();
    }
    if (i < N_NODES) {
        const int pos = bsum[blockIdx.x] + sh[t] - d;
        row_ptr[i] = pos;
        cursor[i]  = pos;
        invd[i]    = 1.0f / fmaxf((float)d, 1.0f);
    }
}

__global__ void fill_csr_kernel(const int* __restrict__ ei, const int* __restrict__ flag,
                                int* __restrict__ cursor, int* __restrict__ ssrc) {
    int e = (blockIdx.x * blockDim.x + threadIdx.x) * 2;
    if (e >= N_EDGES) return;
    int is64 = *flag;
    int s0, s1, d0, d1;
    if (is64) {
        int4 sv = *(const int4*)(ei + 2 * (size_t)e);
        int4 dv = *(const int4*)(ei + 2 * ((size_t)N_EDGES + e));
        s0 = sv.x; s1 = sv.z; d0 = dv.x; d1 = dv.z;
    } else {
        int2 sv = *(const int2*)(ei + (size_t)e);
        int2 dv = *(const int2*)(ei + (size_t)N_EDGES + e);
        s0 = sv.x; s1 = sv.y; d0 = dv.x; d1 = dv.y;
    }
    ssrc[atomicAdd(&cursor[d0], 1)] = s0;
    ssrc[atomicAdd(&cursor[d1], 1)] = s1;
}

// ===========================================================================
// FULL (bf16-direct) path kernels
// ===========================================================================

// x (fp32) -> xb (bf16), N*128 elems
__global__ void convert_xb_kernel(const float* __restrict__ x, u16* __restrict__ xb) {
    const int n4 = N_NODES * D_IN / 4;
    int i = blockIdx.x * 256 + threadIdx.x;
    if (i >= n4) return;
    float4 v = ((const float4*)x)[i];
    ushort4 o;
    o.x = f2bf_u(v.x); o.y = f2bf_u(v.y); o.z = f2bf_u(v.z); o.w = f2bf_u(v.w);
    ((ushort4*)xb)[i] = o;
}

// all weights -> bf16, k-blocked layout: WT[kb][col][32] (kb = k/32).
// WT3 = [W3_l | W3_r | 0pad] (128 cols x 256 k)
__global__ void build_wt_kernel(const float* __restrict__ W1l, const float* __restrict__ W1r,
                                const float* __restrict__ W2l, const float* __restrict__ W2r,
                                const float* __restrict__ W3l, const float* __restrict__ W3r,
                                u16* __restrict__ wt1l, u16* __restrict__ wt1r,
                                u16* __restrict__ wt2l, u16* __restrict__ wt2r,
                                u16* __restrict__ wt3) {
    int idx = blockIdx.x * 256 + threadIdx.x;
    if (idx < 65536) {                       // WT1l / WT1r : NC=256, K=128
        int seg = idx >> 15, d = idx & 32767;
        int kb = d >> 13, col = (d >> 5) & 255, kq = d & 31;
        int k = kb * 32 + kq;
        const float* W = seg ? W1r : W1l;
        u16* WT = seg ? wt1r : wt1l;
        WT[d] = f2bf_u(W[k * 256 + col]);
    } else if (idx < 196608) {               // WT2l / WT2r : NC=256, K=256
        int d = idx - 65536;
        int seg = d >> 16; d &= 65535;
        int kb = d >> 13, col = (d >> 5) & 255, kq = d & 31;
        int k = kb * 32 + kq;
        const float* W = seg ? W2r : W2l;
        u16* WT = seg ? wt2r : wt2l;
        WT[d] = f2bf_u(W[k * 256 + col]);
    } else if (idx < 229376) {               // WT3 : NC=128, K=256, zero-padded
        int d = idx - 196608;
        int kb = d >> 12, col = (d >> 5) & 127, kq = d & 31;
        int k = kb * 32 + kq;
        float v = 0.f;
        if (col < 47)      v = W3l[k * 47 + col];
        else if (col < 94) v = W3r[k * 47 + (col - 47)];
        wt3[d] = f2bf_u(v);
    }
}

// CSR gather-mean over bf16 rows: one wave per node, half-wave edge pairing
// (R11 structure; at the L2-miss service-rate floor, kept as-is).
template <int CC>
__global__ __launch_bounds__(256) void gather_mean_bf(
    const u16* __restrict__ Xb, const int* __restrict__ rp,
    const int* __restrict__ ssrc, const float* __restrict__ invd,
    u16* __restrict__ agg)
{
    const int w = (blockIdx.x * 256 + threadIdx.x) >> 6;
    const int lane = threadIdx.x & 63;
    if (w >= N_NODES) return;
    const int start = rp[w], end = rp[w + 1];
    const float sc = invd[w];
    const int l5 = lane & 31, half = lane >> 5;

    if constexpr (CC == 256) {
        const u16* base = Xb + l5 * 8;          // 32 lanes x 8 u16 = 512B row
        float a[8];
#pragma unroll
        for (int i = 0; i < 8; ++i) a[i] = 0.f;

        int e = start;
        for (; e + 7 < end; e += 8) {           // 4 pairs: 4 loads in flight/lane
            bf16x8 v0 = *(const bf16x8*)(base + (size_t)ssrc[e     + half] * 256);
            bf16x8 v1 = *(const bf16x8*)(base + (size_t)ssrc[e + 2 + half] * 256);
            bf16x8 v2 = *(const bf16x8*)(base + (size_t)ssrc[e + 4 + half] * 256);
            bf16x8 v3 = *(const bf16x8*)(base + (size_t)ssrc[e + 6 + half] * 256);
#pragma unroll
            for (int i = 0; i < 8; ++i)
                a[i] += (bf2f((u16)v0[i]) + bf2f((u16)v1[i]))
                      + (bf2f((u16)v2[i]) + bf2f((u16)v3[i]));
        }
        for (; e < end; e += 2) {               // pair tail (half 1 may idle)
            if (e + half < end) {
                bf16x8 v = *(const bf16x8*)(base + (size_t)ssrc[e + half] * 256);
#pragma unroll
                for (int i = 0; i < 8; ++i) a[i] += bf2f((u16)v[i]);
            }
        }
#pragma unroll
        for (int i = 0; i < 8; ++i) a[i] += __shfl_xor(a[i], 32);
        if (half == 0) {
            bf16x8 o;
#pragma unroll
            for (int i = 0; i < 8; ++i) o[i] = (short)f2bf_u(a[i] * sc);
            *(bf16x8*)(agg + (size_t)w * 256 + l5 * 8) = o;
        }
    } else {  // CC == 128: 32 lanes x 4 u16 = 256B row
        const u16* base = Xb + l5 * 4;
        float a[4];
#pragma unroll
        for (int i = 0; i < 4; ++i) a[i] = 0.f;

        int e = start;
        for (; e + 7 < end; e += 8) {
            ushort4 v0 = *(const ushort4*)(base + (size_t)ssrc[e     + half] * 128);
            ushort4 v1 = *(const ushort4*)(base + (size_t)ssrc[e + 2 + half] * 128);
            ushort4 v2 = *(const ushort4*)(base + (size_t)ssrc[e + 4 + half] * 128);
            ushort4 v3 = *(const ushort4*)(base + (size_t)ssrc[e + 6 + half] * 128);
            a[0] += (bf2f(v0.x) + bf2f(v1.x)) + (bf2f(v2.x) + bf2f(v3.x));
            a[1] += (bf2f(v0.y) + bf2f(v1.y)) + (bf2f(v2.y) + bf2f(v3.y));
            a[2] += (bf2f(v0.z) + bf2f(v1.z)) + (bf2f(v2.z) + bf2f(v3.z));
            a[3] += (bf2f(v0.w) + bf2f(v1.w)) + (bf2f(v2.w) + bf2f(v3.w));
        }
        for (; e < end; e += 2) {
            if (e + half < end) {
                ushort4 v = *(const ushort4*)(base + (size_t)ssrc[e + half] * 128);
                a[0] += bf2f(v.x); a[1] += bf2f(v.y);
                a[2] += bf2f(v.z); a[3] += bf2f(v.w);
            }
        }
#pragma unroll
        for (int i = 0; i < 4; ++i) a[i] += __shfl_xor(a[i], 32);
        if (half == 0) {
            ushort4 o;
            o.x = f2bf_u(a[0] * sc); o.y = f2bf_u(a[1] * sc);
            o.z = f2bf_u(a[2] * sc); o.w = f2bf_u(a[3] * sc);
            *(ushort4*)(agg + (size_t)w * 128 + l5 * 4) = o;
        }
    }
}

// ---------------------------------------------------------------------------
// LDS-staged bf16 MFMA GEMM, T3+T4 (proven R8): counted vmcnt + XCD swizzle.
// split>0 path: cols<split -> bf16 U rows via Cb, stride UPADB=64 u16 (128B
// = exactly 2 aligned cache lines per downstream random gather read — HALVES
// the gas kernel's L2-miss traffic, the measured limiter).
// ---------------------------------------------------------------------------
template <int NK0, int NK1, int NC>
__global__ __launch_bounds__(256, 2) void mfma_lds(
    const u16* __restrict__ A0, const u16* __restrict__ WT0,
    const u16* __restrict__ A1, const u16* __restrict__ WT1,
    const float* __restrict__ bias,
    const float* __restrict__ gamma, const float* __restrict__ beta,
    const float* __restrict__ mean, const float* __restrict__ var,
    float* __restrict__ C, int M, int do_bias, int bn_relu,
    u16* __restrict__ Cb, float* __restrict__ C2, int split)
{
    __shared__ __align__(16) char lds[24576];   // A dbuf @0/8192, B dbuf @16384/20480

    constexpr int NYB = (N_NODES + 127) / 128;  // 391 row-panels
    constexpr int nxb = NC / 64;                // col-blocks per row-panel

    // ---- XCD col-sibling swizzle (1-D grid, nxb*8*ceil(NYB/8) blocks)
    const int bid  = blockIdx.x;
    const int xcd  = bid & 7;
    const int slot = bid >> 3;
    const int cb   = slot % nxb;
    const int yg   = slot / nxb;
    const int yb   = yg * 8 + xcd;
    if (yb >= NYB) return;                      // pad guard (uniform per block)

    const int t = threadIdx.x;
    const int wv = t >> 6, lane = t & 63;
    const int lr = lane & 15, quad = lane >> 4;
    const int row0 = yb * 128;
    const int col0 = cb * 64;
    constexpr int NKT = NK0 + NK1;

    // ---- per-thread stage constants
    // A: 2 slots of 16B (8KB tile); B: 1 slot of 16B (4KB tile)
    int sIdxA[2], sCsA[2];
#pragma unroll
    for (int i = 0; i < 2; ++i) {
        int slotA = i * 256 + t;           // 0..511
        sIdxA[i] = slotA >> 2;             // row 0..127
        int c = slotA & 3;
        sCsA[i] = c ^ ((sIdxA[i] >> 1) & 3);
    }
    int srowA[2];
#pragma unroll
    for (int i = 0; i < 2; ++i) {
        int r = row0 + sIdxA[i];
        srowA[i] = (r < N_NODES) ? r : (N_NODES - 1);   // clamp (garbage rows unused)
    }
    const int sIdxB = t >> 2;              // col 0..63
    const int sCsB  = (t & 3) ^ ((sIdxB >> 1) & 3);

    // ---- ds_read byte offsets within a tile (swizzled chunk)
    int offA[2], offB[4];
#pragma unroll
    for (int r = 0; r < 2; ++r) {
        int idx = wv * 32 + r * 16 + lr;
        offA[r] = idx * 64 + ((quad ^ ((idx >> 1) & 3)) * 16);
    }
#pragma unroll
    for (int c = 0; c < 4; ++c) {
        int idx = c * 16 + lr;
        offB[c] = idx * 64 + ((quad ^ ((idx >> 1) & 3)) * 16);
    }

    floatx4 acc[2][4];
#pragma unroll
    for (int r = 0; r < 2; ++r)
#pragma unroll
        for (int c = 0; c < 4; ++c) acc[r][c] = (floatx4){0.f, 0.f, 0.f, 0.f};

    // ---- stage k-step ks into buffer 'cur' (3 loads/thread, vmcnt-tracked)
    auto stage = [&](int ks, int cur) {
        const char* Ab; const char* Wb; int kb; size_t Kb;  // Kb = row stride bytes
        if (ks < NK0) { Ab = (const char*)A0; Wb = (const char*)WT0; kb = ks;       Kb = (size_t)NK0 * 64; }
        else          { Ab = (const char*)A1; Wb = (const char*)WT1; kb = ks - NK0; Kb = (size_t)NK1 * 64; }
#pragma unroll
        for (int i = 0; i < 2; ++i) {
            const char* srcA = Ab + (size_t)srowA[i] * Kb + (size_t)kb * 64 + sCsA[i] * 16;
            load_lds16(srcA, lds + cur * 8192 + (i * 256 + t) * 16);
        }
        const char* srcB = Wb + ((size_t)kb * NC + col0 + sIdxB) * 64 + sCsB * 16;
        load_lds16(srcB, lds + 16384 + cur * 4096 + t * 16);
    };

    // ---- compute current buffer: 2 A-frags + 4 B-frags + 8 MFMA
    auto compute = [&](int cur) {
        const char* la = lds + cur * 8192;
        const char* lb = lds + 16384 + cur * 4096;
        bf16x8 a[2], b[4];
#pragma unroll
        for (int r = 0; r < 2; ++r) a[r] = *(const bf16x8*)(la + offA[r]);
#pragma unroll
        for (int c = 0; c < 4; ++c) b[c] = *(const bf16x8*)(lb + offB[c]);
#pragma unroll
        for (int c = 0; c < 4; ++c) {
            acc[0][c] = __builtin_amdgcn_mfma_f32_16x16x32_bf16(a[0], b[c], acc[0][c], 0, 0, 0);
            acc[1][c] = __builtin_amdgcn_mfma_f32_16x16x32_bf16(a[1], b[c], acc[1][c], 0, 0, 0);
        }
    };

    // ---- T4 counted-vmcnt main loop: stages ks and ks+1 in flight; never
    //      drain to 0 until the final stage.
    stage(0, 0);
    if constexpr (NKT > 1) stage(1, 1);
#pragma unroll
    for (int ks = 0; ks < NKT; ++ks) {
        if (ks < NKT - 1) {
            asm volatile("s_waitcnt vmcnt(3)" ::: "memory");   // stage ks landed (3 of ks+1 in flight)
        } else {
            asm volatile("s_waitcnt vmcnt(0)" ::: "memory");   // final stage
        }
        __builtin_amdgcn_s_barrier();        // all waves' stage(ks) visible
        __builtin_amdgcn_sched_barrier(0);   // pin: no hoist of ds_read above barrier
        compute(ks & 1);
        if (ks + 2 < NKT) {
            __builtin_amdgcn_s_barrier();    // all waves done reading buf[ks&1]
            stage(ks + 2, ks & 1);           // refill freed buffer; loads fly on
        }
    }

    // ---- epilogue (C/D: col=lr, row=quad*4+g) — proven round-0 mapping
#pragma unroll
    for (int r = 0; r < 2; ++r) {
#pragma unroll
        for (int g = 0; g < 4; ++g) {
            const int row = row0 + wv * 32 + r * 16 + quad * 4 + g;
            if (row >= N_NODES) continue;
#pragma unroll
            for (int c = 0; c < 4; ++c) {
                const int col = col0 + c * 16 + lr;
                float v = acc[r][c][g];
                if (split > 0) {
                    if (col < split) {
                        Cb[(size_t)row * UPADB + col] = f2bf_u(v);   // bf16 U, 128B rows
                    } else if (col < 2 * split) {
                        C2[(size_t)row * split + (col - split)] = v + bias[col - split];
                    }
                } else {
                    if (col >= M) continue;
                    if (do_bias) v += bias[col];
                    if (bn_relu) {
                        v = (v - mean[col]) * (gamma[col] * rsqrtf(var[col] + BN_EPS)) + beta[col];
                        v = fmaxf(v, 0.0f);
                    }
                    const size_t off = (size_t)row * M + col;
                    C[off] = v;
                    if (Cb) Cb[off] = f2bf_u(v);
                }
            }
        }
    }
}

// ===========================================================================
// SAFE path kernels (R5, proven)
// ===========================================================================
template <int CC>
__global__ __launch_bounds__(256) void gather_mean(
    const float* __restrict__ X, int ldx,
    const int* __restrict__ rp, const int* __restrict__ ssrc,
    const float* __restrict__ invd, float* __restrict__ agg)
{
    const long long gid = (long long)blockIdx.x * blockDim.x + threadIdx.x;
    const int w = (int)(gid >> 6);
    const int lane = threadIdx.x & 63;
    if (w >= N_NODES) return;
    const int start = rp[w], end = rp[w + 1];
    const float sc = invd[w];

    if constexpr (CC == 256) {
        const float* base = X + lane * 4;
        float4 a = make_float4(0.f, 0.f, 0.f, 0.f);
        int e = start;
        for (; e + 1 < end; e += 2) {
            int s0 = ssrc[e], s1 = ssrc[e + 1];
            float4 v0 = *(const float4*)(base + (long long)s0 * ldx);
            float4 v1 = *(const float4*)(base + (long long)s1 * ldx);
            a.x += v0.x + v1.x; a.y += v0.y + v1.y;
            a.z += v0.z + v1.z; a.w += v0.w + v1.w;
        }
        if (e < end) {
            float4 v = *(const float4*)(base + (long long)ssrc[e] * ldx);
            a.x += v.x; a.y += v.y; a.z += v.z; a.w += v.w;
        }
        float4 o = make_float4(a.x * sc, a.y * sc, a.z * sc, a.w * sc);
        *(float4*)(agg + (long long)w * 256 + lane * 4) = o;
    } else {
        const float* base = X + lane * 2;
        float2 a = make_float2(0.f, 0.f);
        int e = start;
        for (; e + 1 < end; e += 2) {
            int s0 = ssrc[e], s1 = ssrc[e + 1];
            float2 v0 = *(const float2*)(base + (long long)s0 * ldx);
            float2 v1 = *(const float2*)(base + (long long)s1 * ldx);
            a.x += v0.x + v1.x; a.y += v0.y + v1.y;
        }
        if (e < end) {
            float2 v = *(const float2*)(base + (long long)ssrc[e] * ldx);
            a.x += v.x; a.y += v.y;
        }
        float2 o = make_float2(a.x * sc, a.y * sc);
        *(float2*)(agg + (long long)w * 128 + lane * 2) = o;
    }
}

#define GBM 128
#define GBN 64
#define GBK 32
#define LDA 40
#define LDB 40

__global__ __launch_bounds__(256) void mfma_gemm(
    const float* __restrict__ A0, const float* __restrict__ B0, int K0,
    const float* __restrict__ A1, const float* __restrict__ B1, int K1,
    const float* __restrict__ bias,
    const float* __restrict__ gamma, const float* __restrict__ beta,
    const float* __restrict__ mean, const float* __restrict__ var,
    float* __restrict__ C, int M, int do_bias, int bn_relu)
{
    __shared__ short As[GBM * LDA];
    __shared__ short Bs[GBN * LDB];

    const int t = threadIdx.x;
    const int wv = t >> 6;
    const int lane = t & 63;
    const int row0 = blockIdx.y * GBM;
    const int col0 = blockIdx.x * GBN;

    const int lr = lane & 15;
    const int lk = (lane >> 4) * 8;

    floatx4 acc[2][4];
#pragma unroll
    for (int r = 0; r < 2; ++r)
#pragma unroll
        for (int c = 0; c < 4; ++c) acc[r][c] = (floatx4){0.f, 0.f, 0.f, 0.f};

    const int arow = t >> 3;
    const int akc  = (t & 7) * 4;
    const int bkr  = t >> 4;
    const int bcc  = (t & 15) * 4;

    for (int pass = 0; pass < 2; ++pass) {
        if (pass == 1 && A1 == nullptr) break;
        const float* __restrict__ A = pass ? A1 : A0;
        const float* __restrict__ B = pass ? B1 : B0;
        const int K = pass ? K1 : K0;

        for (int k0 = 0; k0 < K; k0 += GBK) {
            __syncthreads();
#pragma unroll
            for (int i = 0; i < 4; ++i) {
                const int lrow = arow + i * 32;
                const int grow = row0 + lrow;
                float4 v = make_float4(0.f, 0.f, 0.f, 0.f);
                if (grow < N_NODES)
                    v = *(const float4*)(A + (long long)grow * K + k0 + akc);
                short4 sv;
                sv.x = f2bf(v.x); sv.y = f2bf(v.y);
                sv.z = f2bf(v.z); sv.w = f2bf(v.w);
                *(short4*)(&As[lrow * LDA + akc]) = sv;
            }
#pragma unroll
            for (int i = 0; i < 2; ++i) {
                const int k = bkr + i * 16;
                const int gc = col0 + bcc;
                float4 v;
                if (gc + 3 < M) {
                    v = *(const float4*)(B + (long long)(k0 + k) * M + gc);
                } else {
                    v.x = (gc + 0 < M) ? B[(long long)(k0 + k) * M + gc + 0] : 0.f;
                    v.y = (gc + 1 < M) ? B[(long long)(k0 + k) * M + gc + 1] : 0.f;
                    v.z = (gc + 2 < M) ? B[(long long)(k0 + k) * M + gc + 2] : 0.f;
                    v.w = (gc + 3 < M) ? B[(long long)(k0 + k) * M + gc + 3] : 0.f;
                }
                Bs[(bcc + 0) * LDB + k] = f2bf(v.x);
                Bs[(bcc + 1) * LDB + k] = f2bf(v.y);
                Bs[(bcc + 2) * LDB + k] = f2bf(v.z);
                Bs[(bcc + 3) * LDB + k] = f2bf(v.w);
            }
            __syncthreads();

            bf16x8 af[2], bfr[4];
#pragma unroll
            for (int r = 0; r < 2; ++r)
                af[r] = *(const bf16x8*)(&As[(wv * 32 + r * 16 + lr) * LDA + lk]);
#pragma unroll
            for (int c = 0; c < 4; ++c)
                bfr[c] = *(const bf16x8*)(&Bs[(c * 16 + lr) * LDB + lk]);
#pragma unroll
            for (int r = 0; r < 2; ++r)
#pragma unroll
                for (int c = 0; c < 4; ++c)
                    acc[r][c] = __builtin_amdgcn_mfma_f32_16x16x32_bf16(
                        af[r], bfr[c], acc[r][c], 0, 0, 0);
        }
    }

#pragma unroll
    for (int r = 0; r < 2; ++r) {
#pragma unroll
        for (int g = 0; g < 4; ++g) {
            const int row = row0 + wv * 32 + r * 16 + (lane >> 4) * 4 + g;
            if (row >= N_NODES) continue;
#pragma unroll
            for (int c = 0; c < 4; ++c) {
                const int col = col0 + c * 16 + lr;
                if (col >= M) continue;
                float v = acc[r][c][g];
                if (do_bias) v += bias[col];
                if (bn_relu) {
                    v = (v - mean[col]) * (gamma[col] * rsqrtf(var[col] + BN_EPS)) + beta[col];
                    v = fmaxf(v, 0.0f);
                }
                C[(long long)row * M + col] = v;
            }
        }
    }
}

// ---------------------------------------------------------------------------
// fused epilogue: gather-add U into z, then log_softmax on the completed
// row IN-WAVE. BF=true: U is bf16 with row stride ldu u16 (FULL path,
// 128B rows -> 2 cache lines per random read, HALF the fp32 miss traffic).
// BF=false: U fp32 stride ldu (SAFE path).
// ---------------------------------------------------------------------------
template <bool BF>
__global__ __launch_bounds__(256) void gather_add_softmax(
    const void* __restrict__ Uv, int ldu, const int* __restrict__ rp,
    const int* __restrict__ ssrc, const float* __restrict__ invd,
    float* __restrict__ z, float* __restrict__ y)
{
    const int w = (blockIdx.x * 256 + threadIdx.x) >> 6;
    const int lane = threadIdx.x & 63;
    if (w >= N_NODES) return;
    const bool act = lane < D_OUT;
    const int start = rp[w], end = rp[w + 1];

    float a0 = 0.f, a1 = 0.f, a2 = 0.f, a3 = 0.f;
    float a4 = 0.f, a5 = 0.f, a6 = 0.f, a7 = 0.f;
    if (act) {
        if constexpr (BF) {
            const u16* Ub = (const u16*)Uv + lane;
            int e = start;
            for (; e + 7 < end; e += 8) {
                a0 += bf2f(Ub[(size_t)ssrc[e]     * ldu]);
                a1 += bf2f(Ub[(size_t)ssrc[e + 1] * ldu]);
                a2 += bf2f(Ub[(size_t)ssrc[e + 2] * ldu]);
                a3 += bf2f(Ub[(size_t)ssrc[e + 3] * ldu]);
                a4 += bf2f(Ub[(size_t)ssrc[e + 4] * ldu]);
                a5 += bf2f(Ub[(size_t)ssrc[e + 5] * ldu]);
                a6 += bf2f(Ub[(size_t)ssrc[e + 6] * ldu]);
                a7 += bf2f(Ub[(size_t)ssrc[e + 7] * ldu]);
            }
            for (; e < end; ++e) a0 += bf2f(Ub[(size_t)ssrc[e] * ldu]);
        } else {
            const float* Ub = (const float*)Uv + lane;
            int e = start;
            for (; e + 7 < end; e += 8) {
                a0 += Ub[(size_t)ssrc[e]     * ldu];
                a1 += Ub[(size_t)ssrc[e + 1] * ldu];
                a2 += Ub[(size_t)ssrc[e + 2] * ldu];
                a3 += Ub[(size_t)ssrc[e + 3] * ldu];
                a4 += Ub[(size_t)ssrc[e + 4] * ldu];
                a5 += Ub[(size_t)ssrc[e + 5] * ldu];
                a6 += Ub[(size_t)ssrc[e + 6] * ldu];
                a7 += Ub[(size_t)ssrc[e + 7] * ldu];
            }
            for (; e < end; ++e) a0 += Ub[(size_t)ssrc[e] * ldu];
        }
    }
    // all 64 lanes converge here for the wave reductions
    float zv = 0.f;
    if (act) {
        zv = z[(long long)w * D_OUT + lane]
           + (((a0 + a1) + (a2 + a3)) + ((a4 + a5) + (a6 + a7))) * invd[w];
        z[(long long)w * D_OUT + lane] = zv;
    }

    float v = act ? zv : -INFINITY;
    float m = v;
#pragma unroll
    for (int off = 32; off > 0; off >>= 1) m = fmaxf(m, __shfl_down(m, off));
    m = __shfl(m, 0);

    float ev = act ? expf(v - m) : 0.0f;
    float s = ev;
#pragma unroll
    for (int off = 32; off > 0; off >>= 1) s += __shfl_down(s, off);
    s = __shfl(s, 0);

    if (act) y[(long long)w * D_OUT + lane] = v - m - logf(s);
}

// ---------------------------------------------------------------------------
// launch
// ---------------------------------------------------------------------------
extern "C" void kernel_launch(void* const* d_in, const int* in_sizes, int n_in,
                              void* d_out, int out_size, void* d_ws, size_t ws_size,
                              hipStream_t stream) {
    const float* x     = (const float*)d_in[0];
    const int*   ei    = (const int*)d_in[1];
    const float* W1_l  = (const float*)d_in[2];
    const float* b1    = (const float*)d_in[3];
    const float* W1_r  = (const float*)d_in[4];
    const float* bn1_g = (const float*)d_in[5];
    const float* bn1_b = (const float*)d_in[6];
    const float* bn1_m = (const float*)d_in[7];
    const float* bn1_v = (const float*)d_in[8];
    const float* W2_l  = (const float*)d_in[9];
    const float* b2    = (const float*)d_in[10];
    const float* W2_r  = (const float*)d_in[11];
    const float* bn2_g = (const float*)d_in[12];
    const float* bn2_b = (const float*)d_in[13];
    const float* bn2_m = (const float*)d_in[14];
    const float* bn2_v = (const float*)d_in[15];
    const float* W3_l  = (const float*)d_in[16];
    const float* b3    = (const float*)d_in[17];
    const float* W3_r  = (const float*)d_in[18];

    // --- common workspace (CSR) ---
    char* ws = (char*)d_ws;
    int*   degi    = (int*)(ws + 0);
    int*   row_ptr = (int*)(ws + 200064);
    int*   cursor  = (int*)(ws + 400128);
    float* invd    = (float*)(ws + 600192);
    int*   flag    = (int*)(ws + 800256);
    int*   bsum    = (int*)(ws + 800320);
    int*   ssrc    = (int*)(ws + 801152);          // 3.2 MB -> ends 4,001,152

    // d_out layout: z [N*47] | y_pred [N*47] | S1 [N*256] | S2 [N*256]
    float* z     = (float*)d_out;
    float* ypred = z + (long long)N_NODES * D_OUT;
    float* S1    = ypred + (long long)N_NODES * D_OUT;
    float* S2    = S1 + (long long)N_NODES * D_HID;

    // --- CSR build (shared) ---
    detect_idx_kernel<<<1, 256, 0, stream>>>(ei, flag);
    hipMemsetAsync(degi, 0, N_NODES * sizeof(int), stream);
    const int eblocks2 = (N_EDGES / 2 + 255) / 256;
    count_deg_kernel<<<eblocks2, 256, 0, stream>>>(ei, flag, degi);
    block_sum_kernel<<<SCAN_NBLK, 256, 0, stream>>>(degi, bsum);
    scan_bsums_kernel<<<1, 256, 0, stream>>>(bsum, row_ptr);
    fill_rowptr_kernel<<<SCAN_NBLK, 256, 0, stream>>>(degi, bsum, row_ptr, cursor, invd);
    fill_csr_kernel<<<eblocks2, 256, 0, stream>>>(ei, flag, cursor, ssrc);

    const int gblocks = (N_NODES * 64 + 255) / 256;

    // FULL bf16-direct plan needs 94,059,904 B of ws
    if (ws_size >= 94059904ULL) {
        u16*   wt1l = (u16*)(ws + 4001152);
        u16*   wt1r = (u16*)(ws + 4066688);
        u16*   wt2l = (u16*)(ws + 4132224);
        u16*   wt2r = (u16*)(ws + 4263296);
        u16*   wt3  = (u16*)(ws + 4394368);
        u16*   xb   = (u16*)(ws + 4459904);        // N*128 bf16
        u16*   S1b  = (u16*)(ws + 17259904);       // N*256 bf16
        u16*   S2b  = (u16*)(ws + 42859904);       // N*256 bf16
        u16*   agg  = (u16*)(ws + 68459904);       // N*256 bf16 (reused as bf16 U, UPADB=64: 6.4MB)
        u16*   Ub   = agg;

        convert_xb_kernel<<<(N_NODES * D_IN / 4 + 255) / 256, 256, 0, stream>>>(x, xb);
        build_wt_kernel<<<(229376 + 255) / 256, 256, 0, stream>>>(
            W1_l, W1_r, W2_l, W2_r, W3_l, W3_r, wt1l, wt1r, wt2l, wt2r, wt3);

        // 1-D swizzled grids: nxb * 8 * ceil(391/8) blocks
        const int nHid = 4 * 8 * 49;   // NC=256 -> 1568 (4 early-return)
        const int nOut = 2 * 8 * 49;   // NC=128 -> 784  (2 early-return)

        // layer 1 (K=128 x2 passes, NKT=8)
        gather_mean_bf<128><<<gblocks, 256, 0, stream>>>(xb, row_ptr, ssrc, invd, agg);
        mfma_lds<4, 4, 256><<<nHid, 256, 0, stream>>>(
            agg, wt1l, xb, wt1r,
            b1, bn1_g, bn1_b, bn1_m, bn1_v,
            S1, D_HID, 1, 1, S1b, nullptr, 0);
        // layer 2 (K=256 x2 passes, NKT=16)
        gather_mean_bf<256><<<gblocks, 256, 0, stream>>>(S1b, row_ptr, ssrc, invd, agg);
        mfma_lds<8, 8, 256><<<nHid, 256, 0, stream>>>(
            agg, wt2l, S1b, wt2r,
            b2, bn2_g, bn2_b, bn2_m, bn2_v,
            S2, D_HID, 1, 1, S2b, nullptr, 0);
        // layer 3 (fused transform-first: Ub = bf16(S2@W3_l) [stride 64], z = S2@W3_r + b3)
        mfma_lds<8, 0, 128><<<nOut, 256, 0, stream>>>(
            S2b, wt3, nullptr, nullptr,
            b3, nullptr, nullptr, nullptr, nullptr,
            nullptr, 94, 0, 0, Ub, z, D_OUT);
        gather_add_softmax<true><<<gblocks, 256, 0, stream>>>(
            Ub, UPADB, row_ptr, ssrc, invd, z, ypred);
    } else {
        // SAFE: R5 fp32-LDS pipeline (proven <= 55.2 MB)
        float* aggF = (float*)(ws + 4001152);      // N*256 fp32, ends 55,201,152
        float* U    = aggF;

        const dim3 gHid(D_HID / GBN, (N_NODES + GBM - 1) / GBM);
        const dim3 gOut(1, (N_NODES + GBM - 1) / GBM);

        gather_mean<128><<<gblocks, 256, 0, stream>>>(x, D_IN, row_ptr, ssrc, invd, aggF);
        mfma_gemm<<<gHid, 256, 0, stream>>>(aggF, W1_l, D_IN, x, W1_r, D_IN,
                                            b1, bn1_g, bn1_b, bn1_m, bn1_v,
                                            S1, D_HID, 1, 1);
        gather_mean<256><<<gblocks, 256, 0, stream>>>(S1, D_HID, row_ptr, ssrc, invd, aggF);
        mfma_gemm<<<gHid, 256, 0, stream>>>(aggF, W2_l, D_HID, S1, W2_r, D_HID,
                                            b2, bn2_g, bn2_b, bn2_m, bn2_v,
                                            S2, D_HID, 1, 1);
        mfma_gemm<<<gOut, 256, 0, stream>>>(S2, W3_l, D_HID, nullptr, nullptr, 0,
                                            nullptr, nullptr, nullptr, nullptr, nullptr,
                                            U, D_OUT, 0, 0);
        mfma_gemm<<<gOut, 256, 0, stream>>>(S2, W3_r, D_HID, nullptr, nullptr, 0,
                                            b3, nullptr, nullptr, nullptr, nullptr,
                                            z, D_OUT, 1, 0);
        gather_add_softmax<false><<<gblocks, 256, 0, stream>>>(
            U, D_OUT, row_ptr, ssrc, invd, z, ypred);
    }
}